// Round 16
// baseline (151.601 us; speedup 1.0000x reference)
//
#include <hip/hip_runtime.h>

typedef unsigned long long u64;
typedef int i32x4 __attribute__((ext_vector_type(4)));

#define HW    3136      // 56*56 ; 3136 % 64 == 0
#define CIN   256
#define CMID  768
#define EPSV  1e-5

__device__ __forceinline__ u64 shfl_xor64(u64 v, int m) {
  unsigned lo = (unsigned)__shfl_xor((int)(unsigned)v, m);
  unsigned hi = (unsigned)__shfl_xor((int)(v >> 32), m);
  return ((u64)hi << 32) | lo;
}

// 16 sign bits -> 16 i8 bytes (bit=1 -> 0xFF(-1), bit=0 -> 0x01(+1))  [R9-verified]
__device__ __forceinline__ i32x4 unpack16(unsigned bits) {
  i32x4 r;
  #pragma unroll
  for (int q = 0; q < 4; ++q) {
    unsigned nib    = (bits >> (4 * q)) & 0xFu;
    unsigned spread = (nib * 0x00204081u) & 0x01010101u;
    unsigned d      = 0x01010101u ^ ((spread << 8) - (spread << 1));
    r[q] = (int)d;
  }
  return r;
}

// ---------------------------------------------------------------------------
// prep: weights -> i8 sign matrices in MFMA-FRAGMENT-TILED layout (R13):
//   tile = 16 rows x 64 k; byte [tile*1024 + lane*16 + j].
// BN folded to (inv, c): y_bn = y*inv + c.
// ---------------------------------------------------------------------------
__global__ __launch_bounds__(64) void prep_kernel(
    const float* __restrict__ w1, const float* __restrict__ w2,
    const float* __restrict__ g1, const float* __restrict__ b1,
    const float* __restrict__ m1, const float* __restrict__ v1,
    const float* __restrict__ g2, const float* __restrict__ b2,
    const float* __restrict__ m2, const float* __restrict__ v2,
    char* __restrict__ w1t, char* __restrict__ w2t,
    float2* __restrict__ ic1, float2* __restrict__ ic2)
{
  int blk = blockIdx.x, lane = threadIdx.x;
  if (blk < 384) {
    const float* src;
    char* dst;
    int row, k0, ldk;
    if (blk < 192) {                      // W1: 48 row-tiles x 4 k-tiles
      int rt = blk >> 2, kt = blk & 3;
      row = rt * 16 + (lane & 15);
      k0  = kt * 64 + (lane >> 4) * 16;
      src = w1; ldk = 256; dst = w1t + (size_t)blk * 1024;
    } else {                              // W2: 16 row-tiles x 12 k-tiles
      int tid = blk - 192;
      int rt = tid / 12, kt = tid - rt * 12;
      row = rt * 16 + (lane & 15);
      k0  = kt * 64 + (lane >> 4) * 16;
      src = w2; ldk = 768; dst = w2t + (size_t)tid * 1024;
    }
    const float* sp = src + (size_t)row * ldk + k0;
    unsigned d[4];
    #pragma unroll
    for (int q = 0; q < 4; ++q) {
      unsigned dv = 0;
      #pragma unroll
      for (int j = 0; j < 4; ++j) {
        float v = sp[q * 4 + j];
        unsigned s = (v < 0.f) ? 0xFFu : (v > 0.f ? 1u : 0u);
        dv |= s << (8 * j);
      }
      d[q] = dv;
    }
    i32x4 vv; vv.x = (int)d[0]; vv.y = (int)d[1]; vv.z = (int)d[2]; vv.w = (int)d[3];
    *(i32x4*)(dst + lane * 16) = vv;
  } else {
    int i = (blk - 384) * 64 + lane;
    if (i < CMID) {
      double inv = (double)g1[i] / sqrt((double)v1[i] + EPSV);
      float2 o; o.x = (float)inv;
      o.y = (float)((double)b1[i] - (double)m1[i] * inv);
      ic1[i] = o;
    } else if (i < CMID + CIN) {
      int j = i - CMID;
      double inv = (double)g2[j] / sqrt((double)v2[j] + EPSV);
      float2 o; o.x = (float)inv;
      o.y = (float)((double)b2[j] - (double)m2[j] * inv);
      ic2[j] = o;
    }
  }
}

// ---------------------------------------------------------------------------
// k1: pack x -> i8 LDS, layer-1 GEMM, bit-packed sign epilogue (R9-verified),
// write gsy[px][12] u64 to global (9.6 MB, L3-resident). LDS 16 KB only.
// ---------------------------------------------------------------------------
__global__ __launch_bounds__(256, 4) void l1_kernel(
    const float* __restrict__ x, const char* __restrict__ w1t,
    const float2* __restrict__ ic1, u64* __restrict__ gsy)
{
  __shared__ __align__(16) char sBx[64 * 256];   // 16 KB, swizzled

  int t    = threadIdx.x;
  int w    = t >> 6;
  int lane = t & 63;
  int l15  = lane & 15;
  int g4   = lane >> 4;
  int swz  = l15 << 4;
  int lb   = lane << 4;

  int px0 = blockIdx.x * 64;           // 1568*64 == 100352
  int b   = px0 / HW;
  int hw0 = px0 - b * HW;
  const float* xb = x + (size_t)b * (CIN * HW) + hw0;

  // ---- pack: thread packs px=lane, chans [64w,64w+64) -> i8 {-1,0,1} ----
  {
    const float* xp = xb + lane + (size_t)(w << 6) * HW;
    int rowbase = lane * 256 + (w << 6);
    int pswz    = (lane & 15) << 4;
    #pragma unroll
    for (int j = 0; j < 4; ++j) {
      unsigned d[4];
      #pragma unroll
      for (int q = 0; q < 4; ++q) {
        unsigned dv = 0;
        #pragma unroll
        for (int bb = 0; bb < 4; ++bb) {
          int c = j * 16 + q * 4 + bb;
          unsigned u = __float_as_uint(xp[(size_t)c * HW]);
          unsigned s = ((u + u) == 0u) ? 0u : (((int)u < 0) ? 0xFFu : 1u);
          dv |= s << (8 * bb);
        }
        d[q] = dv;
      }
      i32x4 v; v.x = (int)d[0]; v.y = (int)d[1]; v.z = (int)d[2]; v.w = (int)d[3];
      *(i32x4*)&sBx[(rowbase + j * 16) ^ pswz] = v;
    }
  }
  __syncthreads();

  // ---- layer 1: wave rows [192w,+192) in 6 chunks of 32; bit epilogue ----
  u64 syb[4][3];
  #pragma unroll
  for (int n = 0; n < 4; ++n)
    #pragma unroll
    for (int j = 0; j < 3; ++j) syb[n][j] = 0ull;

  #pragma unroll 1
  for (int ch = 0; ch < 6; ++ch) {
    int rt0 = w * 12 + ch * 2;
    i32x4 acc[2][4];
    #pragma unroll
    for (int m = 0; m < 2; ++m)
      #pragma unroll
      for (int n = 0; n < 4; ++n) acc[m][n] = (i32x4)0;

    #pragma unroll
    for (int ks = 0; ks < 4; ++ks) {
      int k0 = ks * 64 + g4 * 16;
      i32x4 bf[4];
      #pragma unroll
      for (int n = 0; n < 4; ++n)
        bf[n] = *(const i32x4*)&sBx[((n * 16 + l15) * 256 + k0) ^ swz];
      i32x4 af[2];
      #pragma unroll
      for (int m = 0; m < 2; ++m)
        af[m] = *(const i32x4*)&w1t[(size_t)((rt0 + m) * 4 + ks) * 1024 + lb];
      #pragma unroll
      for (int m = 0; m < 2; ++m)
        #pragma unroll
        for (int n = 0; n < 4; ++n)
          acc[m][n] = __builtin_amdgcn_mfma_i32_16x16x64_i8(
              af[m], bf[n], acc[m][n], 0, 0, 0);
    }

    #pragma unroll
    for (int m = 0; m < 2; ++m) {
      int base = ch * 32 + m * 16;               // compile-time 0..176
      int wd   = base >> 6;                      // 0..2
      int bo   = base & 63;
      int r0   = w * 192 + base + g4 * 4;
      float2 c0 = ic1[r0], c1 = ic1[r0 + 1], c2 = ic1[r0 + 2], c3 = ic1[r0 + 3];
      #pragma unroll
      for (int n = 0; n < 4; ++n) {
        float y0 = fmaf((float)acc[m][n].x, c0.x, c0.y);
        float y1 = fmaf((float)acc[m][n].y, c1.x, c1.y);
        float y2 = fmaf((float)acc[m][n].z, c2.x, c2.y);
        float y3 = fmaf((float)acc[m][n].w, c3.x, c3.y);
        unsigned nib = (y0 < 0.f ? 1u : 0u) | (y1 < 0.f ? 2u : 0u)
                     | (y2 < 0.f ? 4u : 0u) | (y3 < 0.f ? 8u : 0u);
        syb[n][wd] |= (u64)nib << (bo + g4 * 4);
      }
    }
  }

  // OR-reduce across g4 groups, then store 3 words per (w, n) slice
  #pragma unroll
  for (int n = 0; n < 4; ++n)
    #pragma unroll
    for (int j = 0; j < 3; ++j) {
      u64 v = syb[n][j];
      v |= shfl_xor64(v, 16);
      v |= shfl_xor64(v, 32);
      syb[n][j] = v;
    }
  if (g4 < 3) {
    #pragma unroll
    for (int n = 0; n < 4; ++n)
      gsy[(size_t)(px0 + n * 16 + l15) * 12 + 3 * w + g4] = syb[n][g4];
  }
}

// ---------------------------------------------------------------------------
// k2: stage gsy bits -> LDS (coalesced), unpack16 -> B-frags, layer-2 GEMM,
// BN + residual + store (full 256B-line stores). LDS 6.7 KB.
// ---------------------------------------------------------------------------
__global__ __launch_bounds__(256, 4) void l2_kernel(
    const float* __restrict__ x, const char* __restrict__ w2t,
    const float2* __restrict__ ic2, const u64* __restrict__ gsy,
    float* __restrict__ out)
{
  __shared__ u64 ssy[64][13];          // pad 13 (R9 layout)

  int t    = threadIdx.x;
  int w    = t >> 6;
  int lane = t & 63;
  int l15  = lane & 15;
  int g4   = lane >> 4;
  int lb   = lane << 4;

  int px0 = blockIdx.x * 64;
  int b   = px0 / HW;
  int hw0 = px0 - b * HW;
  const float* xb = x   + (size_t)b * (CIN * HW) + hw0;
  float*       ob = out + (size_t)b * (CIN * HW) + hw0;

  // stage: contiguous 6 KB read
  for (int i = t; i < 768; i += 256) {
    int px = i / 12;
    ssy[px][i - px * 12] = gsy[(size_t)px0 * 12 + i];
  }
  __syncthreads();

  int rbase = w << 6;
  i32x4 acc[4][4];
  #pragma unroll
  for (int m = 0; m < 4; ++m)
    #pragma unroll
    for (int n = 0; n < 4; ++n) acc[m][n] = (i32x4)0;

  #pragma unroll 4
  for (int ks = 0; ks < 12; ++ks) {
    i32x4 bf[4];
    #pragma unroll
    for (int n = 0; n < 4; ++n) {
      u64 wv = ssy[n * 16 + l15][ks];
      unsigned bits = (unsigned)(wv >> (g4 * 16)) & 0xFFFFu;
      bf[n] = unpack16(bits);
    }
    i32x4 af[4];
    #pragma unroll
    for (int m = 0; m < 4; ++m)
      af[m] = *(const i32x4*)&w2t[(size_t)((w * 4 + m) * 12 + ks) * 1024 + lb];
    #pragma unroll
    for (int m = 0; m < 4; ++m)
      #pragma unroll
      for (int n = 0; n < 4; ++n)
        acc[m][n] = __builtin_amdgcn_mfma_i32_16x16x64_i8(
            af[m], bf[n], acc[m][n], 0, 0, 0);
  }

  #pragma unroll
  for (int m = 0; m < 4; ++m) {
    int r0 = rbase + m * 16 + g4 * 4;
    float2 c0 = ic2[r0], c1 = ic2[r0 + 1], c2 = ic2[r0 + 2], c3 = ic2[r0 + 3];
    #pragma unroll
    for (int n = 0; n < 4; ++n) {
      int pxo = n * 16 + l15;
      const float* xq = xb + pxo;
      float*       oq = ob + pxo;
      size_t o0 = (size_t)r0 * HW;
      oq[o0]          = fmaf((float)acc[m][n].x, c0.x, c0.y) + xq[o0];
      oq[o0 + HW]     = fmaf((float)acc[m][n].y, c1.x, c1.y) + xq[o0 + HW];
      oq[o0 + 2 * HW] = fmaf((float)acc[m][n].z, c2.x, c2.y) + xq[o0 + 2 * HW];
      oq[o0 + 3 * HW] = fmaf((float)acc[m][n].w, c3.x, c3.y) + xq[o0 + 3 * HW];
    }
  }
}

// ---------------------------------------------------------------------------
// fallback: R13 fused kernel verbatim (used only if ws_size can't hold gsy)
// ---------------------------------------------------------------------------
__global__ __launch_bounds__(256, 2) void bnn_fused_kernel(
    const float* __restrict__ x,
    const char* __restrict__ w1t, const char* __restrict__ w2t,
    const float2* __restrict__ ic1, const float2* __restrict__ ic2,
    float* __restrict__ out)
{
  __shared__ __align__(16) char sBx[64 * 256];
  __shared__ __align__(16) char sY[64 * 768];

  int t    = threadIdx.x;
  int w    = t >> 6;
  int lane = t & 63;
  int l15  = lane & 15;
  int g4   = lane >> 4;
  int swz  = l15 << 4;
  int lb   = lane << 4;

  int px0 = blockIdx.x * 64;
  int b   = px0 / HW;
  int hw0 = px0 - b * HW;
  const float* xb = x   + (size_t)b * (CIN * HW) + hw0;
  float*       ob = out + (size_t)b * (CIN * HW) + hw0;

  {
    const float* xp = xb + lane + (size_t)(w << 6) * HW;
    int rowbase = lane * 256 + (w << 6);
    int pswz    = (lane & 15) << 4;
    #pragma unroll
    for (int j = 0; j < 4; ++j) {
      unsigned d[4];
      #pragma unroll
      for (int q = 0; q < 4; ++q) {
        unsigned dv = 0;
        #pragma unroll
        for (int bb = 0; bb < 4; ++bb) {
          int c = j * 16 + q * 4 + bb;
          unsigned u = __float_as_uint(xp[(size_t)c * HW]);
          unsigned s = ((u + u) == 0u) ? 0u : (((int)u < 0) ? 0xFFu : 1u);
          dv |= s << (8 * bb);
        }
        d[q] = dv;
      }
      i32x4 v; v.x = (int)d[0]; v.y = (int)d[1]; v.z = (int)d[2]; v.w = (int)d[3];
      *(i32x4*)&sBx[(rowbase + j * 16) ^ pswz] = v;
    }
  }
  __syncthreads();

  i32x4 bfa[4][4];
  #pragma unroll
  for (int ks = 0; ks < 4; ++ks) {
    int k0 = ks * 64 + g4 * 16;
    #pragma unroll
    for (int n = 0; n < 4; ++n)
      bfa[ks][n] = *(const i32x4*)&sBx[((n * 16 + l15) * 256 + k0) ^ swz];
  }

  #pragma unroll 1
  for (int ch = 0; ch < 4; ++ch) {
    int rt0 = w * 12 + ch * 3;
    i32x4 acc[3][4];
    #pragma unroll
    for (int m = 0; m < 3; ++m)
      #pragma unroll
      for (int n = 0; n < 4; ++n) acc[m][n] = (i32x4)0;

    #pragma unroll
    for (int ks = 0; ks < 4; ++ks) {
      i32x4 af[3];
      #pragma unroll
      for (int m = 0; m < 3; ++m)
        af[m] = *(const i32x4*)&w1t[(size_t)((rt0 + m) * 4 + ks) * 1024 + lb];
      #pragma unroll
      for (int m = 0; m < 3; ++m)
        #pragma unroll
        for (int n = 0; n < 4; ++n)
          acc[m][n] = __builtin_amdgcn_mfma_i32_16x16x64_i8(
              af[m], bfa[ks][n], acc[m][n], 0, 0, 0);
    }

    #pragma unroll
    for (int m = 0; m < 3; ++m) {
      int r0 = (rt0 + m) * 16 + g4 * 4;
      float2 c0 = ic1[r0], c1 = ic1[r0 + 1], c2 = ic1[r0 + 2], c3 = ic1[r0 + 3];
      #pragma unroll
      for (int n = 0; n < 4; ++n) {
        int px = n * 16 + l15;
        float y0 = fmaf((float)acc[m][n].x, c0.x, c0.y);
        float y1 = fmaf((float)acc[m][n].y, c1.x, c1.y);
        float y2 = fmaf((float)acc[m][n].z, c2.x, c2.y);
        float y3 = fmaf((float)acc[m][n].w, c3.x, c3.y);
        unsigned dv =
            (unsigned)(y0 < 0.f ? 0xFFu : (y0 > 0.f ? 1u : 0u))
          | ((unsigned)(y1 < 0.f ? 0xFFu : (y1 > 0.f ? 1u : 0u)) << 8)
          | ((unsigned)(y2 < 0.f ? 0xFFu : (y2 > 0.f ? 1u : 0u)) << 16)
          | ((unsigned)(y3 < 0.f ? 0xFFu : (y3 > 0.f ? 1u : 0u)) << 24);
        *(unsigned*)&sY[(px * 768 + r0) ^ swz] = dv;
      }
    }
  }
  __syncthreads();

  {
    int rbase = w << 6;
    i32x4 acc[4][4];
    #pragma unroll
    for (int m = 0; m < 4; ++m)
      #pragma unroll
      for (int n = 0; n < 4; ++n) acc[m][n] = (i32x4)0;

    #pragma unroll 4
    for (int ks = 0; ks < 12; ++ks) {
      int k0 = ks * 64 + g4 * 16;
      i32x4 bf[4];
      #pragma unroll
      for (int n = 0; n < 4; ++n)
        bf[n] = *(const i32x4*)&sY[((n * 16 + l15) * 768 + k0) ^ swz];
      i32x4 af[4];
      #pragma unroll
      for (int m = 0; m < 4; ++m)
        af[m] = *(const i32x4*)&w2t[(size_t)((w * 4 + m) * 12 + ks) * 1024 + lb];
      #pragma unroll
      for (int m = 0; m < 4; ++m)
        #pragma unroll
        for (int n = 0; n < 4; ++n)
          acc[m][n] = __builtin_amdgcn_mfma_i32_16x16x64_i8(
              af[m], bf[n], acc[m][n], 0, 0, 0);
    }

    #pragma unroll
    for (int m = 0; m < 4; ++m) {
      int r0 = rbase + m * 16 + g4 * 4;
      float2 c0 = ic2[r0], c1 = ic2[r0 + 1], c2 = ic2[r0 + 2], c3 = ic2[r0 + 3];
      #pragma unroll
      for (int n = 0; n < 4; ++n) {
        int pxo = n * 16 + l15;
        const float* xq = xb + pxo;
        float*       oq = ob + pxo;
        size_t o0 = (size_t)r0 * HW;
        oq[o0]          = fmaf((float)acc[m][n].x, c0.x, c0.y) + xq[o0];
        oq[o0 + HW]     = fmaf((float)acc[m][n].y, c1.x, c1.y) + xq[o0 + HW];
        oq[o0 + 2 * HW] = fmaf((float)acc[m][n].z, c2.x, c2.y) + xq[o0 + 2 * HW];
        oq[o0 + 3 * HW] = fmaf((float)acc[m][n].w, c3.x, c3.y) + xq[o0 + 3 * HW];
      }
    }
  }
}

extern "C" void kernel_launch(void* const* d_in, const int* in_sizes, int n_in,
                              void* d_out, int out_size, void* d_ws, size_t ws_size,
                              hipStream_t stream) {
  const float* x  = (const float*)d_in[0];
  const float* w1 = (const float*)d_in[1];
  const float* w2 = (const float*)d_in[2];
  const float* g1 = (const float*)d_in[3];
  const float* b1 = (const float*)d_in[4];
  const float* m1 = (const float*)d_in[5];
  const float* v1 = (const float*)d_in[6];
  const float* g2 = (const float*)d_in[7];
  const float* b2 = (const float*)d_in[8];
  const float* m2 = (const float*)d_in[9];
  const float* v2 = (const float*)d_in[10];
  float* out = (float*)d_out;

  char*   w1t = (char*)d_ws;               // 196608 B
  char*   w2t = w1t + 196608;              // 196608 B
  float2* ic1 = (float2*)(w2t + 196608);   // 768*8 B
  float2* ic2 = ic1 + CMID;                // 256*8 B
  u64*    gsy = (u64*)(ic2 + CIN);         // 100352*12*8 = 9,633,792 B

  prep_kernel<<<400, 64, 0, stream>>>(w1, w2, g1, b1, m1, v1,
                                      g2, b2, m2, v2, w1t, w2t, ic1, ic2);

  size_t need = 196608u * 2 + 8192u + (size_t)100352 * 12 * 8;
  if (ws_size >= need) {
    l1_kernel<<<1568, 256, 0, stream>>>(x, w1t, ic1, gsy);
    l2_kernel<<<1568, 256, 0, stream>>>(x, w2t, ic2, gsy, out);
  } else {
    bnn_fused_kernel<<<1568, 256, 0, stream>>>(x, w1t, w2t, ic1, ic2, out);
  }
}

// Round 17
// 106.213 us; speedup vs baseline: 1.4273x; 1.4273x over previous
//
#include <hip/hip_runtime.h>

typedef unsigned long long u64;
typedef int i32x4 __attribute__((ext_vector_type(4)));

#define HW    3136      // 56*56 ; 3136 % 64 == 0
#define CIN   256
#define CMID  768
#define EPSV  1e-5

// static-index accessor for float4 under full unroll
#define GETC(V, J) ((J) == 0 ? (V).x : (J) == 1 ? (V).y : (J) == 2 ? (V).z : (V).w)

// ---------------------------------------------------------------------------
// prep: weights -> i8 sign matrices in MFMA-FRAGMENT-TILED layout (R13):
//   tile = 16 rows x 64 k; byte [tile*1024 + lane*16 + j] = sign of
//   w[row = tile_r*16 + (lane&15)][k = tile_k*64 + (lane>>4)*16 + j].
// BN folded to (inv, c): y_bn = y*inv + c.
// ---------------------------------------------------------------------------
__global__ __launch_bounds__(64) void prep_kernel(
    const float* __restrict__ w1, const float* __restrict__ w2,
    const float* __restrict__ g1, const float* __restrict__ b1,
    const float* __restrict__ m1, const float* __restrict__ v1,
    const float* __restrict__ g2, const float* __restrict__ b2,
    const float* __restrict__ m2, const float* __restrict__ v2,
    char* __restrict__ w1t, char* __restrict__ w2t,
    float2* __restrict__ ic1, float2* __restrict__ ic2)
{
  int blk = blockIdx.x, lane = threadIdx.x;
  if (blk < 384) {
    const float* src;
    char* dst;
    int row, k0, ldk;
    if (blk < 192) {                      // W1: 48 row-tiles x 4 k-tiles
      int rt = blk >> 2, kt = blk & 3;
      row = rt * 16 + (lane & 15);
      k0  = kt * 64 + (lane >> 4) * 16;
      src = w1; ldk = 256; dst = w1t + (size_t)blk * 1024;
    } else {                              // W2: 16 row-tiles x 12 k-tiles
      int tid = blk - 192;
      int rt = tid / 12, kt = tid - rt * 12;
      row = rt * 16 + (lane & 15);
      k0  = kt * 64 + (lane >> 4) * 16;
      src = w2; ldk = 768; dst = w2t + (size_t)tid * 1024;
    }
    const float* sp = src + (size_t)row * ldk + k0;
    unsigned d[4];
    #pragma unroll
    for (int q = 0; q < 4; ++q) {
      unsigned dv = 0;
      #pragma unroll
      for (int j = 0; j < 4; ++j) {
        float v = sp[q * 4 + j];
        unsigned s = (v < 0.f) ? 0xFFu : (v > 0.f ? 1u : 0u);
        dv |= s << (8 * j);
      }
      d[q] = dv;
    }
    i32x4 vv; vv.x = (int)d[0]; vv.y = (int)d[1]; vv.z = (int)d[2]; vv.w = (int)d[3];
    *(i32x4*)(dst + lane * 16) = vv;
  } else {
    int i = (blk - 384) * 64 + lane;
    if (i < CMID) {
      double inv = (double)g1[i] / sqrt((double)v1[i] + EPSV);
      float2 o; o.x = (float)inv;
      o.y = (float)((double)b1[i] - (double)m1[i] * inv);
      ic1[i] = o;
    } else if (i < CMID + CIN) {
      int j = i - CMID;
      double inv = (double)g2[j] / sqrt((double)v2[j] + EPSV);
      float2 o; o.x = (float)inv;
      o.y = (float)((double)b2[j] - (double)m2[j] * inv);
      ic2[j] = o;
    }
  }
}

// ---------------------------------------------------------------------------
// main: R13 structure verbatim (1568 blocks x 4 waves, 64-px tile, fused
// L1+L2 on MFMA, sBx/sY XOR-swizzled, fragment-tiled coalesced weights).
// ONE change vs R13: pack loads x via float4 along px (4 px x 16 chans per
// thread) -> 16 dwordx4 wave-instructions instead of 64 dword (4x fewer VMEM
// instrs, 4 full 256B lines per instruction). sBx layout unchanged.
// ---------------------------------------------------------------------------
__global__ __launch_bounds__(256, 2) void bnn_kernel(
    const float* __restrict__ x,
    const char* __restrict__ w1t, const char* __restrict__ w2t,
    const float2* __restrict__ ic1, const float2* __restrict__ ic2,
    float* __restrict__ out)
{
  __shared__ __align__(16) char sBx[64 * 256];   // 16 KB
  __shared__ __align__(16) char sY[64 * 768];    // 48 KB  (total 64 KB)

  int t    = threadIdx.x;
  int w    = t >> 6;
  int lane = t & 63;
  int l15  = lane & 15;
  int g4   = lane >> 4;
  int swz  = l15 << 4;
  int lb   = lane << 4;

  int px0 = blockIdx.x * 64;           // 1568*64 == 100352 exactly
  int b   = px0 / HW;
  int hw0 = px0 - b * HW;
  const float* xb = x   + (size_t)b * (CIN * HW) + hw0;
  float*       ob = out + (size_t)b * (CIN * HW) + hw0;

  // ---- pack (vectorized): thread -> px group [4*pxg,+4), chans [16h,+16) ----
  {
    int pxg = t & 15;                  // 16 groups of 4 px = 64 px
    int h   = t >> 4;                  // 16 groups of 16 chans = 256 chans
    const float* xp = xb + pxg * 4 + (size_t)(h << 4) * HW;
    unsigned accq[4][4];               // [px_j][dword q] — static-indexed

    #pragma unroll
    for (int q = 0; q < 4; ++q) {      // chan chunk: chans 16h + 4q .. +4
      float4 v0 = *(const float4*)&xp[(size_t)(q * 4 + 0) * HW];
      float4 v1 = *(const float4*)&xp[(size_t)(q * 4 + 1) * HW];
      float4 v2 = *(const float4*)&xp[(size_t)(q * 4 + 2) * HW];
      float4 v3 = *(const float4*)&xp[(size_t)(q * 4 + 3) * HW];
      #pragma unroll
      for (int j = 0; j < 4; ++j) {    // px within group
        unsigned dv = 0;
        #pragma unroll
        for (int cc = 0; cc < 4; ++cc) {
          float f = (cc == 0) ? GETC(v0, j) : (cc == 1) ? GETC(v1, j)
                  : (cc == 2) ? GETC(v2, j) : GETC(v3, j);
          unsigned u = __float_as_uint(f);
          unsigned s = ((u + u) == 0u) ? 0u : (((int)u < 0) ? 0xFFu : 1u);
          dv |= s << (8 * cc);
        }
        accq[j][q] = dv;
      }
    }
    #pragma unroll
    for (int j = 0; j < 4; ++j) {
      int px = pxg * 4 + j;
      i32x4 v;
      v.x = (int)accq[j][0]; v.y = (int)accq[j][1];
      v.z = (int)accq[j][2]; v.w = (int)accq[j][3];
      *(i32x4*)&sBx[(px * 256 + (h << 4)) ^ ((px & 15) << 4)] = v;
    }
  }
  __syncthreads();

  // ---- hoist B-fragments (whole K=256) ----
  i32x4 bfa[4][4];                     // [ks][n]
  #pragma unroll
  for (int ks = 0; ks < 4; ++ks) {
    int k0 = ks * 64 + g4 * 16;
    #pragma unroll
    for (int n = 0; n < 4; ++n)
      bfa[ks][n] = *(const i32x4*)&sBx[((n * 16 + l15) * 256 + k0) ^ swz];
  }

  // ---- layer 1: 4 chunks of 48 rows; coalesced tiled-A loads ----
  #pragma unroll 1
  for (int ch = 0; ch < 4; ++ch) {
    int rt0 = w * 12 + ch * 3;
    i32x4 acc[3][4];
    #pragma unroll
    for (int m = 0; m < 3; ++m)
      #pragma unroll
      for (int n = 0; n < 4; ++n) acc[m][n] = (i32x4)0;

    #pragma unroll
    for (int ks = 0; ks < 4; ++ks) {
      i32x4 af[3];
      #pragma unroll
      for (int m = 0; m < 3; ++m)
        af[m] = *(const i32x4*)&w1t[(size_t)((rt0 + m) * 4 + ks) * 1024 + lb];
      #pragma unroll
      for (int m = 0; m < 3; ++m)
        #pragma unroll
        for (int n = 0; n < 4; ++n)
          acc[m][n] = __builtin_amdgcn_mfma_i32_16x16x64_i8(
              af[m], bfa[ks][n], acc[m][n], 0, 0, 0);
    }

    // epilogue: BN-threshold -> i8 sign bytes into sY
    #pragma unroll
    for (int m = 0; m < 3; ++m) {
      int r0 = (rt0 + m) * 16 + g4 * 4;
      float2 c0 = ic1[r0], c1 = ic1[r0 + 1], c2 = ic1[r0 + 2], c3 = ic1[r0 + 3];
      #pragma unroll
      for (int n = 0; n < 4; ++n) {
        int px = n * 16 + l15;
        float y0 = fmaf((float)acc[m][n].x, c0.x, c0.y);
        float y1 = fmaf((float)acc[m][n].y, c1.x, c1.y);
        float y2 = fmaf((float)acc[m][n].z, c2.x, c2.y);
        float y3 = fmaf((float)acc[m][n].w, c3.x, c3.y);
        unsigned dv =
            (unsigned)(y0 < 0.f ? 0xFFu : (y0 > 0.f ? 1u : 0u))
          | ((unsigned)(y1 < 0.f ? 0xFFu : (y1 > 0.f ? 1u : 0u)) << 8)
          | ((unsigned)(y2 < 0.f ? 0xFFu : (y2 > 0.f ? 1u : 0u)) << 16)
          | ((unsigned)(y3 < 0.f ? 0xFFu : (y3 > 0.f ? 1u : 0u)) << 24);
        *(unsigned*)&sY[(px * 768 + r0) ^ swz] = dv;
      }
    }
  }
  __syncthreads();

  // ---- layer 2: wave rows [64w,+64), K=768; coalesced tiled-A loads ----
  {
    int rbase = w << 6;
    i32x4 acc[4][4];
    #pragma unroll
    for (int m = 0; m < 4; ++m)
      #pragma unroll
      for (int n = 0; n < 4; ++n) acc[m][n] = (i32x4)0;

    #pragma unroll 4
    for (int ks = 0; ks < 12; ++ks) {
      int k0 = ks * 64 + g4 * 16;
      i32x4 bf[4];
      #pragma unroll
      for (int n = 0; n < 4; ++n)
        bf[n] = *(const i32x4*)&sY[((n * 16 + l15) * 768 + k0) ^ swz];
      i32x4 af[4];
      #pragma unroll
      for (int m = 0; m < 4; ++m)
        af[m] = *(const i32x4*)&w2t[(size_t)((w * 4 + m) * 12 + ks) * 1024 + lb];
      #pragma unroll
      for (int m = 0; m < 4; ++m)
        #pragma unroll
        for (int n = 0; n < 4; ++n)
          acc[m][n] = __builtin_amdgcn_mfma_i32_16x16x64_i8(
              af[m], bf[n], acc[m][n], 0, 0, 0);
    }

    // epilogue: BN + residual + store
    #pragma unroll
    for (int m = 0; m < 4; ++m) {
      int r0 = rbase + m * 16 + g4 * 4;
      float2 c0 = ic2[r0], c1 = ic2[r0 + 1], c2 = ic2[r0 + 2], c3 = ic2[r0 + 3];
      #pragma unroll
      for (int n = 0; n < 4; ++n) {
        int pxo = n * 16 + l15;
        const float* xq = xb + pxo;
        float*       oq = ob + pxo;
        size_t o0 = (size_t)r0 * HW;
        oq[o0]          = fmaf((float)acc[m][n].x, c0.x, c0.y) + xq[o0];
        oq[o0 + HW]     = fmaf((float)acc[m][n].y, c1.x, c1.y) + xq[o0 + HW];
        oq[o0 + 2 * HW] = fmaf((float)acc[m][n].z, c2.x, c2.y) + xq[o0 + 2 * HW];
        oq[o0 + 3 * HW] = fmaf((float)acc[m][n].w, c3.x, c3.y) + xq[o0 + 3 * HW];
      }
    }
  }
}

extern "C" void kernel_launch(void* const* d_in, const int* in_sizes, int n_in,
                              void* d_out, int out_size, void* d_ws, size_t ws_size,
                              hipStream_t stream) {
  const float* x  = (const float*)d_in[0];
  const float* w1 = (const float*)d_in[1];
  const float* w2 = (const float*)d_in[2];
  const float* g1 = (const float*)d_in[3];
  const float* b1 = (const float*)d_in[4];
  const float* m1 = (const float*)d_in[5];
  const float* v1 = (const float*)d_in[6];
  const float* g2 = (const float*)d_in[7];
  const float* b2 = (const float*)d_in[8];
  const float* m2 = (const float*)d_in[9];
  const float* v2 = (const float*)d_in[10];
  float* out = (float*)d_out;

  char*   w1t = (char*)d_ws;               // 196608 B
  char*   w2t = w1t + 196608;              // 196608 B
  float2* ic1 = (float2*)(w2t + 196608);   // 768 * 8 B
  float2* ic2 = ic1 + CMID;                // 256 * 8 B

  prep_kernel<<<400, 64, 0, stream>>>(w1, w2, g1, b1, m1, v1,
                                      g2, b2, m2, v2, w1t, w2t, ic1, ic2);
  bnn_kernel<<<1568, 256, 0, stream>>>(x, w1t, w2t, ic1, ic2, out);
}